// Round 9
// baseline (187.325 us; speedup 1.0000x reference)
//
#include <hip/hip_runtime.h>
#include <math.h>

typedef __attribute__((ext_vector_type(4))) double d4;

// order-preserving float -> uint key (ascending float => ascending uint)
__device__ inline unsigned fkey(float f) {
  unsigned bits = __float_as_uint(f);
  return (bits & 0x80000000u) ? ~bits : (bits | 0x80000000u);
}

// ---------------------------------------------------------------------------
// Kernel 1: fused {probe, gz zeroing, fp64-MFMA GEMM} -> logits & logitsT.
// 1024 thr = 16 waves; wave w owns the 16x16 tile (rb=(w&3)*16, cb=(w>>2)*16).
// DC=32 K-chunks staged in LDS as fp64 with ROW STRIDE 33 (odd) and scalar
// b64 writes -> both staging writes and fragment reads are bank-conflict-free.
// tid<512 stages x-tile, tid>=512 stages W-tile (1 float4 each per chunk).
// Register prefetch 1 chunk ahead; two barriers per chunk (proven structure).
// Accumulation order identical to rounds 5-8 -> bitwise-same logits.
// gz[0..63]=expert counts, gz[64]=ticket: zeroed by block 0 every call.
// ---------------------------------------------------------------------------
__global__ __launch_bounds__(1024, 8) void logits_fused_kernel(
    const float* __restrict__ x, const float* __restrict__ W,
    const float* __restrict__ bias, float* __restrict__ logits,
    float* __restrict__ logitsT, unsigned* __restrict__ gz,
    int N, int D) {
  __shared__ __attribute__((aligned(16))) double xs64[64 * 34];  // 17408 B
  __shared__ __attribute__((aligned(16))) double ws64[64 * 34];  // 17408 B
  __shared__ unsigned s_fl;

  const int tid = threadIdx.x;
  const int tok0 = blockIdx.x * 64;
  const int l = tid & 63;
  const int l15 = l & 15;
  const int lk = l >> 4;

  if (blockIdx.x == 0 && tid < 65) gz[tid] = 0u;   // counts + ticket

  // ---- fused probe: wave 0, scratch in ws64 ----
  double* pA = ws64;        // [16][4]
  double* pB = ws64 + 64;   // [4][16]
  if (tid < 64) {
    pA[l15 * 4 + lk] = (double)(l15 * 4 + lk + 1);
    pB[lk * 16 + l15] = (double)(l15 * 7 + lk * 3 + 2);
  }
  __syncthreads();
  if (tid < 64) {
    double a = pA[l15 * 4 + lk];
    double b = pB[lk * 16 + l15];
    d4 pacc = (d4)0.0;
    pacc = __builtin_amdgcn_mfma_f64_16x16x4f64(a, b, pacc, 0, 0, 0);
    unsigned res = 4;
    for (int m = 3; m >= 0; --m) {
      bool ok = true;
#pragma unroll
      for (int i = 0; i < 4; ++i) {
        int tr_ = (m < 2) ? ((m == 0) ? 4 * lk + i : lk + 4 * i) : l15;
        int tc_ = (m < 2) ? l15 : ((m == 2) ? 4 * lk + i : lk + 4 * i);
        double ref = 0.0;
#pragma unroll
        for (int kk = 0; kk < 4; ++kk) ref += pA[tr_ * 4 + kk] * pB[kk * 16 + tc_];
        ok = ok && (pacc[i] == ref);
      }
      if (__all(ok)) res = (unsigned)m;
    }
    if (l == 0) s_fl = res;
  }
  __syncthreads();
  const unsigned fl = s_fl;
  __syncthreads();   // probe scratch dead before staging reuses ws64

  if (fl < 4u) {
    // ================= MFMA path =================
    const int w = tid >> 6;        // wave 0..15
    const int rb = (w & 3) * 16;   // token-row base
    const int cb = (w >> 2) * 16;  // expert-col base

    d4 acc = (d4)0.0;

    // staging: tid<512 -> x-tile, tid>=512 -> W-tile; 1 float4/thread/chunk
    const int srow = (tid & 511) >> 3;   // 0..63
    const int sc = tid & 7;              // quad 0..7 within 32-wide chunk
    const bool isx = (tid < 512);
    const float* gsrc = isx ? (x + (size_t)(tok0 + srow) * D + sc * 4)
                            : (W + (size_t)srow * D + sc * 4);
    double* ldst = (isx ? xs64 : ws64) + srow * 33 + sc * 4;

    float4 rg = *(const float4*)gsrc;    // chunk 0
    const int nch = D >> 5;              // 32 chunks
    const int xa0 = (rb + l15) * 33 + lk;
    const int ba0 = (cb + l15) * 33 + lk;

    for (int c = 0; c < nch; ++c) {
      // scalar b64 writes (8B aligned, bank-exact at stride 33)
      ldst[0] = (double)rg.x;
      ldst[1] = (double)rg.y;
      ldst[2] = (double)rg.z;
      ldst[3] = (double)rg.w;
      __syncthreads();
      if (c + 1 < nch) rg = *(const float4*)(gsrc + (c + 1) * 32);
#pragma unroll
      for (int s = 0; s < 8; ++s) {
        double a = xs64[xa0 + 4 * s];
        double b = ws64[ba0 + 4 * s];
        acc = __builtin_amdgcn_mfma_f64_16x16x4f64(a, b, acc, 0, 0, 0);
      }
      __syncthreads();
    }

    // ---- epilogue: probed D mapping, bias add (fp64), LDS round-trip ----
    float* ls = (float*)xs64;  // [64][68] fp32 view = 17408 B, exact fit
#pragma unroll
    for (int i = 0; i < 4; ++i) {
      int tr_, tc_;
      if (fl < 2u) { tc_ = l15; tr_ = (fl == 0u) ? 4 * lk + i : lk + 4 * i; }
      else         { tr_ = l15; tc_ = (fl == 2u) ? 4 * lk + i : lk + 4 * i; }
      int col = cb + tc_;
      ls[(rb + tr_) * 68 + col] = (float)(acc[i] + (double)bias[col]);
    }
    __syncthreads();
    {  // row-major stores: 1024 slots, 1/thread
      int row = tid >> 4, c4 = tid & 15;
      float4 v = {ls[row * 68 + c4 * 4 + 0], ls[row * 68 + c4 * 4 + 1],
                  ls[row * 68 + c4 * 4 + 2], ls[row * 68 + c4 * 4 + 3]};
      *(float4*)(logits + (size_t)(tok0 + row) * 64 + c4 * 4) = v;
    }
    {  // transposed stores: 1/thread
      int e = tid >> 4, t4 = tid & 15;
      float4 v = {ls[(t4 * 4 + 0) * 68 + e], ls[(t4 * 4 + 1) * 68 + e],
                  ls[(t4 * 4 + 2) * 68 + e], ls[(t4 * 4 + 3) * 68 + e]};
      *(float4*)(logitsT + (size_t)e * N + tok0 + t4 * 4) = v;
    }
  } else {
    // ============ inline VALU fp64 fallback (never expected) ============
    for (int o = tid; o < 64 * 64; o += 1024) {
      int row = o >> 6, col = o & 63;
      const float* xp = x + (size_t)(tok0 + row) * D;
      const float* wp = W + (size_t)col * D;
      double s = 0.0;
      for (int kk = 0; kk < D; ++kk)
        s = fma((double)xp[kk], (double)wp[kk], s);
      float v = (float)(s + (double)bias[col]);
      logits[(size_t)(tok0 + row) * 64 + col] = v;
      logitsT[(size_t)col * N + tok0 + row] = v;
    }
  }
}

// ---------------------------------------------------------------------------
// Kernel 2: per-expert k-th-largest via 2-bit-digit bisection (16 passes).
// No atomics: per-thread compare counts, packed u64 wave+block reduction.
// ---------------------------------------------------------------------------
template <int KPT4>
__global__ __launch_bounds__(1024) void select_kernel(
    const float* __restrict__ logitsT, unsigned* __restrict__ ukeys,
    int N, int k) {
  __shared__ unsigned long long part[16];
  __shared__ unsigned s_cur;
  const int e = blockIdx.x;
  const int tid = threadIdx.x;
  const int wid = tid >> 6;
  const int lane = tid & 63;

  const float4* src = (const float4*)(logitsT + (size_t)e * N);
  unsigned key[KPT4 > 0 ? KPT4 * 4 : 4];
  if (KPT4 > 0) {
#pragma unroll
    for (int i = 0; i < (KPT4 > 0 ? KPT4 : 1); ++i) {
      float4 v = src[tid + i * 1024];
      key[i * 4 + 0] = fkey(v.x);
      key[i * 4 + 1] = fkey(v.y);
      key[i * 4 + 2] = fkey(v.z);
      key[i * 4 + 3] = fkey(v.w);
    }
  }

  unsigned cur = 0;
  for (int s = 30; s >= 0; s -= 2) {
    unsigned c1 = cur | (1u << s);
    unsigned c2 = cur | (2u << s);
    unsigned c3 = cur | (3u << s);
    unsigned n1 = 0, n2 = 0, n3 = 0;
    if (KPT4 > 0) {
#pragma unroll
      for (int i = 0; i < (KPT4 > 0 ? KPT4 * 4 : 1); ++i) {
        unsigned u = key[i];
        n1 += (u >= c1) ? 1u : 0u;
        n2 += (u >= c2) ? 1u : 0u;
        n3 += (u >= c3) ? 1u : 0u;
      }
    } else {
      for (int i = tid; i < (N >> 2); i += 1024) {
        float4 v = src[i];
        unsigned u0 = fkey(v.x), u1 = fkey(v.y), u2 = fkey(v.z), u3 = fkey(v.w);
        n1 += (u0 >= c1) + (u1 >= c1) + (u2 >= c1) + (u3 >= c1);
        n2 += (u0 >= c2) + (u1 >= c2) + (u2 >= c2) + (u3 >= c2);
        n3 += (u0 >= c3) + (u1 >= c3) + (u2 >= c3) + (u3 >= c3);
      }
    }
    unsigned long long pk = (unsigned long long)n1 |
                            ((unsigned long long)n2 << 21) |
                            ((unsigned long long)n3 << 42);
#pragma unroll
    for (int off = 32; off; off >>= 1) pk += __shfl_xor(pk, off);
    if (lane == 0) part[wid] = pk;
    __syncthreads();
    if (tid == 0) {
      unsigned long long t = 0;
#pragma unroll
      for (int w = 0; w < 16; ++w) t += part[w];
      unsigned m1 = (unsigned)(t & 0x1FFFFFu);
      unsigned m2 = (unsigned)((t >> 21) & 0x1FFFFFu);
      unsigned m3 = (unsigned)(t >> 42);
      unsigned kk = (unsigned)k;
      unsigned nxt = cur;
      if (m3 >= kk) nxt = c3;
      else if (m2 >= kk) nxt = c2;
      else if (m1 >= kk) nxt = c1;
      s_cur = nxt;
    }
    __syncthreads();
    cur = s_cur;
  }
  if (tid == 0) ukeys[e] = cur;
}

// ---------------------------------------------------------------------------
// Kernel 3: assign + per-expert counts + load-balance loss, fused.
// 256 blocks x 1024 thr (16 waves); one wave per token, grid-stride.
// Per-wave LDS hist (lane0-private rows, no atomics needed) -> 64 global
// u32 atomicAdds per block -> last block (ticket gz[64]) computes the loss.
// gz zeroed by logits kernel every call => replay-safe & deterministic.
// ---------------------------------------------------------------------------
__global__ __launch_bounds__(1024) void assign_count_kernel(
    const float* __restrict__ logits, const unsigned* __restrict__ ukeys,
    float* __restrict__ out, unsigned* __restrict__ gz, int N, int nblk) {
  __shared__ unsigned hist[16][64];
  __shared__ unsigned s_last;
  const int tid = threadIdx.x;
  const int wid = tid >> 6;
  const int lane = tid & 63;
  hist[wid][lane] = 0u;
  __syncthreads();

  const unsigned uk = ukeys[lane];
  const int wg = blockIdx.x * 16 + wid;
  const int nw = nblk * 16;
  for (int token = wg; token < N; token += nw) {
    float v = logits[(size_t)token * 64 + lane];
    unsigned u = fkey(v);
    bool cand = (u >= uk);
    float m = cand ? v : -INFINITY;
#pragma unroll
    for (int off = 32; off; off >>= 1) m = fmaxf(m, __shfl_xor(m, off));
    unsigned long long mask = __ballot(cand && (v == m));
    bool sel = (mask != 0ull);
    int minexp = sel ? (__ffsll((long long)mask) - 1) : -1;
    if (lane == 0) {
      out[token] = sel ? m : 0.0f;
      out[N + token] = (float)minexp;
      out[2 * N + token] = sel ? 1.0f : 0.0f;
      if (sel) hist[wid][minexp] += 1u;  // lane0-only, own row: race-free
    }
  }
  __syncthreads();
  if (tid < 64) {
    unsigned c = 0;
#pragma unroll
    for (int w2 = 0; w2 < 16; ++w2) c += hist[w2][tid];
    if (c) atomicAdd(&gz[tid], c);
  }
  __threadfence();
  __syncthreads();
  if (tid == 0) {
    unsigned old = atomicAdd(&gz[64], 1u);
    s_last = (old == (unsigned)(nblk - 1)) ? 1u : 0u;
  }
  __syncthreads();
  if (s_last != 0u) {
    __threadfence();
    if (tid < 64) {
      unsigned c = atomicAdd(&gz[tid], 0u);  // coherent read
      double cd = (double)c;
      double s = cd;
#pragma unroll
      for (int off = 32; off; off >>= 1) s += __shfl_xor(s, off);
      double mean = s / 64.0;
      double d = cd - mean;
      d = d * d;
#pragma unroll
      for (int off = 32; off; off >>= 1) d += __shfl_xor(d, off);
      if (tid == 0) out[3 * (size_t)N] = (float)((d / 64.0) / (mean + 1e-9));
    }
  }
}

extern "C" void kernel_launch(void* const* d_in, const int* in_sizes, int n_in,
                              void* d_out, int out_size, void* d_ws, size_t ws_size,
                              hipStream_t stream) {
  const float* x = (const float*)d_in[0];
  const float* W = (const float*)d_in[1];
  const float* b = (const float*)d_in[2];

  const int E = in_sizes[2];      // 64
  const int D = in_sizes[1] / E;  // 1024
  const int N = in_sizes[0] / D;  // 32768

  int k = (int)((double)N / (double)(E > 1 ? E : 1) * 1.2);
  if (k < 1) k = 1;
  if (k > N) k = N;               // 614

  const size_t NE = (size_t)N * E;
  float* out = (float*)d_out;

  float* logits = (float*)d_ws;        // N*E fp32 (8 MB)
  float* logitsT = logits + NE;        // N*E fp32 (8 MB)
  unsigned* ukeys = (unsigned*)(logitsT + NE);
  unsigned* gz = ukeys + 64;           // 64 counts + 1 ticket

  logits_fused_kernel<<<N / 64, 1024, 0, stream>>>(x, W, b, logits, logitsT,
                                                   gz, N, D);
  if (N == 32768)
    select_kernel<8><<<64, 1024, 0, stream>>>(logitsT, ukeys, N, k);
  else
    select_kernel<0><<<64, 1024, 0, stream>>>(logitsT, ukeys, N, k);
  const int nblk = 256;
  assign_count_kernel<<<nblk, 1024, 0, stream>>>(logits, ukeys, out, gz, N,
                                                 nblk);
}

// Round 10
// 125.870 us; speedup vs baseline: 1.4882x; 1.4882x over previous
//
#include <hip/hip_runtime.h>
#include <math.h>

typedef __attribute__((ext_vector_type(4))) double d4;

// order-preserving float -> uint key (ascending float => ascending uint)
__device__ inline unsigned fkey(float f) {
  unsigned bits = __float_as_uint(f);
  return (bits & 0x80000000u) ? ~bits : (bits | 0x80000000u);
}

// ---------------------------------------------------------------------------
// Kernel 1: fused {probe, fp64-MFMA GEMM} -> logits & logitsT.
// 1024 thr = 16 waves; wave w owns 16x16 tile (rb=(w&3)*16, cb=(w>>2)*16).
// DC=32 K-chunks, fp64 LDS tiles with ROW STRIDE 33 (bank-exact staging
// writes and fragment reads, verified round 9: conflicts 1.73e7 -> 4.8e6).
// NEW: double-buffered LDS, ONE barrier per chunk (T3 2-phase recipe):
//   chunk c: {write c+1 -> buf[c^1]; prefetch c+2 -> regs; MFMA buf[c]; bar}
// Accumulation order identical to rounds 5-9 -> bitwise-same logits.
// ---------------------------------------------------------------------------
__global__ __launch_bounds__(1024, 8) void logits_fused_kernel(
    const float* __restrict__ x, const float* __restrict__ W,
    const float* __restrict__ bias, float* __restrict__ logits,
    float* __restrict__ logitsT, int N, int D) {
  __shared__ __attribute__((aligned(16))) double xbuf[2][64 * 33];  // 33792 B
  __shared__ __attribute__((aligned(16))) double wbuf[2][64 * 33];  // 33792 B
  __shared__ unsigned s_fl;

  const int tid = threadIdx.x;
  const int tok0 = blockIdx.x * 64;
  const int l = tid & 63;
  const int l15 = l & 15;
  const int lk = l >> 4;

  // ---- fused probe: wave 0, scratch in wbuf ----
  double* pA = &wbuf[0][0];        // [16][4]
  double* pB = &wbuf[0][64];       // [4][16]
  if (tid < 64) {
    pA[l15 * 4 + lk] = (double)(l15 * 4 + lk + 1);
    pB[lk * 16 + l15] = (double)(l15 * 7 + lk * 3 + 2);
  }
  __syncthreads();
  if (tid < 64) {
    double a = pA[l15 * 4 + lk];
    double b = pB[lk * 16 + l15];
    d4 pacc = (d4)0.0;
    pacc = __builtin_amdgcn_mfma_f64_16x16x4f64(a, b, pacc, 0, 0, 0);
    unsigned res = 4;
    for (int m = 3; m >= 0; --m) {
      bool ok = true;
#pragma unroll
      for (int i = 0; i < 4; ++i) {
        int tr_ = (m < 2) ? ((m == 0) ? 4 * lk + i : lk + 4 * i) : l15;
        int tc_ = (m < 2) ? l15 : ((m == 2) ? 4 * lk + i : lk + 4 * i);
        double ref = 0.0;
#pragma unroll
        for (int kk = 0; kk < 4; ++kk) ref += pA[tr_ * 4 + kk] * pB[kk * 16 + tc_];
        ok = ok && (pacc[i] == ref);
      }
      if (__all(ok)) res = (unsigned)m;
    }
    if (l == 0) s_fl = res;
  }
  __syncthreads();
  const unsigned fl = s_fl;
  __syncthreads();   // probe scratch dead before staging reuses wbuf

  if (fl < 4u) {
    // ================= MFMA path =================
    const int w = tid >> 6;        // wave 0..15
    const int rb = (w & 3) * 16;   // token-row base
    const int cb = (w >> 2) * 16;  // expert-col base

    d4 acc = (d4)0.0;

    // staging: tid<512 -> x-tile, tid>=512 -> W-tile; 1 float4/thread/chunk
    const int srow = (tid & 511) >> 3;   // 0..63
    const int sc = tid & 7;              // quad 0..7 within 32-wide chunk
    const bool isx = (tid < 512);
    const float* gsrc = isx ? (x + (size_t)(tok0 + srow) * D + sc * 4)
                            : (W + (size_t)srow * D + sc * 4);
    const int ldoff = srow * 33 + sc * 4;

    const int nch = D >> 5;              // 32 chunks
    const int xa0 = (rb + l15) * 33 + lk;
    const int ba0 = (cb + l15) * 33 + lk;

    // prologue: chunk 0 -> buf0; prefetch chunk 1
    float4 rg = *(const float4*)gsrc;
    {
      double* ld = (isx ? &xbuf[0][0] : &wbuf[0][0]) + ldoff;
      ld[0] = (double)rg.x; ld[1] = (double)rg.y;
      ld[2] = (double)rg.z; ld[3] = (double)rg.w;
    }
    if (nch > 1) rg = *(const float4*)(gsrc + 32);
    __syncthreads();

    for (int c = 0; c < nch; ++c) {
      const int cbuf = c & 1;
      const int nb = cbuf ^ 1;
      // ---- stage chunk c+1 into buf[nb]; prefetch chunk c+2 ----
      if (c + 1 < nch) {
        double* ld = (isx ? &xbuf[nb][0] : &wbuf[nb][0]) + ldoff;
        ld[0] = (double)rg.x; ld[1] = (double)rg.y;
        ld[2] = (double)rg.z; ld[3] = (double)rg.w;
        if (c + 2 < nch) rg = *(const float4*)(gsrc + (c + 2) * 32);
      }
      // ---- MFMA phase: 8 K-steps of 4 from buf[cbuf] ----
      const double* xr = &xbuf[cbuf][0];
      const double* wr = &wbuf[cbuf][0];
#pragma unroll
      for (int s = 0; s < 8; ++s) {
        double a = xr[xa0 + 4 * s];
        double b = wr[ba0 + 4 * s];
        acc = __builtin_amdgcn_mfma_f64_16x16x4f64(a, b, acc, 0, 0, 0);
      }
      __syncthreads();
    }

    // ---- epilogue: probed D mapping, bias add (fp64), LDS round-trip ----
    float* ls = (float*)&xbuf[0][0];  // [64][68] fp32 view (17408 B < 33792)
#pragma unroll
    for (int i = 0; i < 4; ++i) {
      int tr_, tc_;
      if (fl < 2u) { tc_ = l15; tr_ = (fl == 0u) ? 4 * lk + i : lk + 4 * i; }
      else         { tr_ = l15; tc_ = (fl == 2u) ? 4 * lk + i : lk + 4 * i; }
      int col = cb + tc_;
      ls[(rb + tr_) * 68 + col] = (float)(acc[i] + (double)bias[col]);
    }
    __syncthreads();
    {  // row-major stores: 1024 slots, 1/thread
      int row = tid >> 4, c4 = tid & 15;
      float4 v = {ls[row * 68 + c4 * 4 + 0], ls[row * 68 + c4 * 4 + 1],
                  ls[row * 68 + c4 * 4 + 2], ls[row * 68 + c4 * 4 + 3]};
      *(float4*)(logits + (size_t)(tok0 + row) * 64 + c4 * 4) = v;
    }
    {  // transposed stores: 1/thread
      int e = tid >> 4, t4 = tid & 15;
      float4 v = {ls[(t4 * 4 + 0) * 68 + e], ls[(t4 * 4 + 1) * 68 + e],
                  ls[(t4 * 4 + 2) * 68 + e], ls[(t4 * 4 + 3) * 68 + e]};
      *(float4*)(logitsT + (size_t)e * N + tok0 + t4 * 4) = v;
    }
  } else {
    // ============ inline VALU fp64 fallback (never expected) ============
    for (int o = tid; o < 64 * 64; o += 1024) {
      int row = o >> 6, col = o & 63;
      const float* xp = x + (size_t)(tok0 + row) * D;
      const float* wp = W + (size_t)col * D;
      double s = 0.0;
      for (int kk = 0; kk < D; ++kk)
        s = fma((double)xp[kk], (double)wp[kk], s);
      float v = (float)(s + (double)bias[col]);
      logits[(size_t)(tok0 + row) * 64 + col] = v;
      logitsT[(size_t)col * N + tok0 + row] = v;
    }
  }
}

// ---------------------------------------------------------------------------
// Kernel 2: per-expert k-th-largest via 2-bit-digit bisection (16 passes).
// No atomics: per-thread compare counts, packed u64 wave+block reduction.
// ---------------------------------------------------------------------------
template <int KPT4>
__global__ __launch_bounds__(1024) void select_kernel(
    const float* __restrict__ logitsT, unsigned* __restrict__ ukeys,
    int N, int k) {
  __shared__ unsigned long long part[16];
  __shared__ unsigned s_cur;
  const int e = blockIdx.x;
  const int tid = threadIdx.x;
  const int wid = tid >> 6;
  const int lane = tid & 63;

  const float4* src = (const float4*)(logitsT + (size_t)e * N);
  unsigned key[KPT4 > 0 ? KPT4 * 4 : 4];
  if (KPT4 > 0) {
#pragma unroll
    for (int i = 0; i < (KPT4 > 0 ? KPT4 : 1); ++i) {
      float4 v = src[tid + i * 1024];
      key[i * 4 + 0] = fkey(v.x);
      key[i * 4 + 1] = fkey(v.y);
      key[i * 4 + 2] = fkey(v.z);
      key[i * 4 + 3] = fkey(v.w);
    }
  }

  unsigned cur = 0;
  for (int s = 30; s >= 0; s -= 2) {
    unsigned c1 = cur | (1u << s);
    unsigned c2 = cur | (2u << s);
    unsigned c3 = cur | (3u << s);
    unsigned n1 = 0, n2 = 0, n3 = 0;
    if (KPT4 > 0) {
#pragma unroll
      for (int i = 0; i < (KPT4 > 0 ? KPT4 * 4 : 1); ++i) {
        unsigned u = key[i];
        n1 += (u >= c1) ? 1u : 0u;
        n2 += (u >= c2) ? 1u : 0u;
        n3 += (u >= c3) ? 1u : 0u;
      }
    } else {
      for (int i = tid; i < (N >> 2); i += 1024) {
        float4 v = src[i];
        unsigned u0 = fkey(v.x), u1 = fkey(v.y), u2 = fkey(v.z), u3 = fkey(v.w);
        n1 += (u0 >= c1) + (u1 >= c1) + (u2 >= c1) + (u3 >= c1);
        n2 += (u0 >= c2) + (u1 >= c2) + (u2 >= c2) + (u3 >= c2);
        n3 += (u0 >= c3) + (u1 >= c3) + (u2 >= c3) + (u3 >= c3);
      }
    }
    unsigned long long pk = (unsigned long long)n1 |
                            ((unsigned long long)n2 << 21) |
                            ((unsigned long long)n3 << 42);
#pragma unroll
    for (int off = 32; off; off >>= 1) pk += __shfl_xor(pk, off);
    if (lane == 0) part[wid] = pk;
    __syncthreads();
    if (tid == 0) {
      unsigned long long t = 0;
#pragma unroll
      for (int w = 0; w < 16; ++w) t += part[w];
      unsigned m1 = (unsigned)(t & 0x1FFFFFu);
      unsigned m2 = (unsigned)((t >> 21) & 0x1FFFFFu);
      unsigned m3 = (unsigned)(t >> 42);
      unsigned kk = (unsigned)k;
      unsigned nxt = cur;
      if (m3 >= kk) nxt = c3;
      else if (m2 >= kk) nxt = c2;
      else if (m1 >= kk) nxt = c1;
      s_cur = nxt;
    }
    __syncthreads();
    cur = s_cur;
  }
  if (tid == 0) ukeys[e] = cur;
}

// ---------------------------------------------------------------------------
// Kernel 3 (round-8 proven): one wave per token; lane = expert.
// ---------------------------------------------------------------------------
__global__ __launch_bounds__(256) void assign_kernel(
    const float* __restrict__ logits, const unsigned* __restrict__ ukeys,
    float* __restrict__ out, int N) {
  const int lane = threadIdx.x & 63;
  const int token = blockIdx.x * 4 + (threadIdx.x >> 6);

  float v = logits[(size_t)token * 64 + lane];
  unsigned u = fkey(v);
  bool cand = (u >= ukeys[lane]);
  float cv = cand ? v : -INFINITY;
  float m = cv;
#pragma unroll
  for (int off = 32; off; off >>= 1) m = fmaxf(m, __shfl_xor(m, off));
  unsigned long long mask = __ballot(cand && (v == m));
  bool sel = (mask != 0ull);
  int minexp = sel ? (__ffsll((long long)mask) - 1) : -1;

  if (lane == 0) {
    out[token] = sel ? m : 0.0f;
    out[N + token] = (float)minexp;
    out[2 * N + token] = sel ? 1.0f : 0.0f;
  }
}

// ---------------------------------------------------------------------------
// Kernel 4 (round-8 proven): counts (LDS histogram, 1 block, float4) + loss.
// ---------------------------------------------------------------------------
__global__ __launch_bounds__(1024) void count_loss_kernel(
    const float* __restrict__ assigned, float* __restrict__ out, int N) {
  __shared__ unsigned hist[16][64];
  const int tid = threadIdx.x;
  const int wid = tid >> 6;
  hist[wid][tid & 63] = 0u;
  __syncthreads();
  const float4* src = (const float4*)assigned;
  for (int i = tid; i < (N >> 2); i += 1024) {
    float4 v = src[i];
    int e0 = (int)v.x, e1 = (int)v.y, e2 = (int)v.z, e3 = (int)v.w;
    if (e0 >= 0) atomicAdd(&hist[wid][e0], 1u);
    if (e1 >= 0) atomicAdd(&hist[wid][e1], 1u);
    if (e2 >= 0) atomicAdd(&hist[wid][e2], 1u);
    if (e3 >= 0) atomicAdd(&hist[wid][e3], 1u);
  }
  __syncthreads();
  if (tid < 64) {
    unsigned c = 0;
#pragma unroll
    for (int w = 0; w < 16; ++w) c += hist[w][tid];
    double cd = (double)c;
    double s = cd;
#pragma unroll
    for (int off = 32; off; off >>= 1) s += __shfl_xor(s, off);
    double mean = s / 64.0;
    double d = cd - mean;
    d = d * d;
#pragma unroll
    for (int off = 32; off; off >>= 1) d += __shfl_xor(d, off);
    if (tid == 0) out[3 * (size_t)N] = (float)((d / 64.0) / (mean + 1e-9));
  }
}

extern "C" void kernel_launch(void* const* d_in, const int* in_sizes, int n_in,
                              void* d_out, int out_size, void* d_ws, size_t ws_size,
                              hipStream_t stream) {
  const float* x = (const float*)d_in[0];
  const float* W = (const float*)d_in[1];
  const float* b = (const float*)d_in[2];

  const int E = in_sizes[2];      // 64
  const int D = in_sizes[1] / E;  // 1024
  const int N = in_sizes[0] / D;  // 32768

  int k = (int)((double)N / (double)(E > 1 ? E : 1) * 1.2);
  if (k < 1) k = 1;
  if (k > N) k = N;               // 614

  const size_t NE = (size_t)N * E;
  float* out = (float*)d_out;

  float* logits = (float*)d_ws;        // N*E fp32 (8 MB)
  float* logitsT = logits + NE;        // N*E fp32 (8 MB)
  unsigned* ukeys = (unsigned*)(logitsT + NE);

  logits_fused_kernel<<<N / 64, 1024, 0, stream>>>(x, W, b, logits, logitsT,
                                                   N, D);
  if (N == 32768)
    select_kernel<8><<<64, 1024, 0, stream>>>(logitsT, ukeys, N, k);
  else
    select_kernel<0><<<64, 1024, 0, stream>>>(logitsT, ukeys, N, k);
  assign_kernel<<<N / 4, 256, 0, stream>>>(logits, ukeys, out, N);
  count_loss_kernel<<<1, 1024, 0, stream>>>(out + N, out, N);
}

// Round 11
// 110.554 us; speedup vs baseline: 1.6944x; 1.1385x over previous
//
#include <hip/hip_runtime.h>
#include <math.h>

typedef __attribute__((ext_vector_type(4))) double d4;

// order-preserving float -> uint key (ascending float => ascending uint)
__device__ inline unsigned fkey(float f) {
  unsigned bits = __float_as_uint(f);
  return (bits & 0x80000000u) ? ~bits : (bits | 0x80000000u);
}

// ---------------------------------------------------------------------------
// Kernel 1 (round-10 proven, UNCHANGED): fused {probe, fp64-MFMA GEMM}.
// 1024 thr = 16 waves; wave w owns 16x16 tile; DC=32 fp64 LDS chunks,
// row stride 33 (bank-exact), double-buffered, one barrier per chunk.
// ---------------------------------------------------------------------------
__global__ __launch_bounds__(1024, 8) void logits_fused_kernel(
    const float* __restrict__ x, const float* __restrict__ W,
    const float* __restrict__ bias, float* __restrict__ logits,
    float* __restrict__ logitsT, int N, int D) {
  __shared__ __attribute__((aligned(16))) double xbuf[2][64 * 33];
  __shared__ __attribute__((aligned(16))) double wbuf[2][64 * 33];
  __shared__ unsigned s_fl;

  const int tid = threadIdx.x;
  const int tok0 = blockIdx.x * 64;
  const int l = tid & 63;
  const int l15 = l & 15;
  const int lk = l >> 4;

  // ---- fused probe: wave 0, scratch in wbuf ----
  double* pA = &wbuf[0][0];        // [16][4]
  double* pB = &wbuf[0][64];       // [4][16]
  if (tid < 64) {
    pA[l15 * 4 + lk] = (double)(l15 * 4 + lk + 1);
    pB[lk * 16 + l15] = (double)(l15 * 7 + lk * 3 + 2);
  }
  __syncthreads();
  if (tid < 64) {
    double a = pA[l15 * 4 + lk];
    double b = pB[lk * 16 + l15];
    d4 pacc = (d4)0.0;
    pacc = __builtin_amdgcn_mfma_f64_16x16x4f64(a, b, pacc, 0, 0, 0);
    unsigned res = 4;
    for (int m = 3; m >= 0; --m) {
      bool ok = true;
#pragma unroll
      for (int i = 0; i < 4; ++i) {
        int tr_ = (m < 2) ? ((m == 0) ? 4 * lk + i : lk + 4 * i) : l15;
        int tc_ = (m < 2) ? l15 : ((m == 2) ? 4 * lk + i : lk + 4 * i);
        double ref = 0.0;
#pragma unroll
        for (int kk = 0; kk < 4; ++kk) ref += pA[tr_ * 4 + kk] * pB[kk * 16 + tc_];
        ok = ok && (pacc[i] == ref);
      }
      if (__all(ok)) res = (unsigned)m;
    }
    if (l == 0) s_fl = res;
  }
  __syncthreads();
  const unsigned fl = s_fl;
  __syncthreads();   // probe scratch dead before staging reuses wbuf

  if (fl < 4u) {
    const int w = tid >> 6;        // wave 0..15
    const int rb = (w & 3) * 16;   // token-row base
    const int cb = (w >> 2) * 16;  // expert-col base

    d4 acc = (d4)0.0;

    const int srow = (tid & 511) >> 3;   // 0..63
    const int sc = tid & 7;              // quad 0..7
    const bool isx = (tid < 512);
    const float* gsrc = isx ? (x + (size_t)(tok0 + srow) * D + sc * 4)
                            : (W + (size_t)srow * D + sc * 4);
    const int ldoff = srow * 33 + sc * 4;

    const int nch = D >> 5;
    const int xa0 = (rb + l15) * 33 + lk;
    const int ba0 = (cb + l15) * 33 + lk;

    float4 rg = *(const float4*)gsrc;
    {
      double* ld = (isx ? &xbuf[0][0] : &wbuf[0][0]) + ldoff;
      ld[0] = (double)rg.x; ld[1] = (double)rg.y;
      ld[2] = (double)rg.z; ld[3] = (double)rg.w;
    }
    if (nch > 1) rg = *(const float4*)(gsrc + 32);
    __syncthreads();

    for (int c = 0; c < nch; ++c) {
      const int cbuf = c & 1;
      const int nb = cbuf ^ 1;
      if (c + 1 < nch) {
        double* ld = (isx ? &xbuf[nb][0] : &wbuf[nb][0]) + ldoff;
        ld[0] = (double)rg.x; ld[1] = (double)rg.y;
        ld[2] = (double)rg.z; ld[3] = (double)rg.w;
        if (c + 2 < nch) rg = *(const float4*)(gsrc + (c + 2) * 32);
      }
      const double* xr = &xbuf[cbuf][0];
      const double* wr = &wbuf[cbuf][0];
#pragma unroll
      for (int s = 0; s < 8; ++s) {
        double a = xr[xa0 + 4 * s];
        double b = wr[ba0 + 4 * s];
        acc = __builtin_amdgcn_mfma_f64_16x16x4f64(a, b, acc, 0, 0, 0);
      }
      __syncthreads();
    }

    // ---- epilogue: probed D mapping, bias add (fp64), LDS round-trip ----
    float* ls = (float*)&xbuf[0][0];  // [64][68] fp32 view
#pragma unroll
    for (int i = 0; i < 4; ++i) {
      int tr_, tc_;
      if (fl < 2u) { tc_ = l15; tr_ = (fl == 0u) ? 4 * lk + i : lk + 4 * i; }
      else         { tr_ = l15; tc_ = (fl == 2u) ? 4 * lk + i : lk + 4 * i; }
      int col = cb + tc_;
      ls[(rb + tr_) * 68 + col] = (float)(acc[i] + (double)bias[col]);
    }
    __syncthreads();
    {
      int row = tid >> 4, c4 = tid & 15;
      float4 v = {ls[row * 68 + c4 * 4 + 0], ls[row * 68 + c4 * 4 + 1],
                  ls[row * 68 + c4 * 4 + 2], ls[row * 68 + c4 * 4 + 3]};
      *(float4*)(logits + (size_t)(tok0 + row) * 64 + c4 * 4) = v;
    }
    {
      int e = tid >> 4, t4 = tid & 15;
      float4 v = {ls[(t4 * 4 + 0) * 68 + e], ls[(t4 * 4 + 1) * 68 + e],
                  ls[(t4 * 4 + 2) * 68 + e], ls[(t4 * 4 + 3) * 68 + e]};
      *(float4*)(logitsT + (size_t)e * N + tok0 + t4 * 4) = v;
    }
  } else {
    // inline VALU fp64 fallback (never expected)
    for (int o = tid; o < 64 * 64; o += 1024) {
      int row = o >> 6, col = o & 63;
      const float* xp = x + (size_t)(tok0 + row) * D;
      const float* wp = W + (size_t)col * D;
      double s = 0.0;
      for (int kk = 0; kk < D; ++kk)
        s = fma((double)xp[kk], (double)wp[kk], s);
      float v = (float)(s + (double)bias[col]);
      logits[(size_t)(tok0 + row) * 64 + col] = v;
      logitsT[(size_t)col * N + tok0 + row] = v;
    }
  }
}

// ---------------------------------------------------------------------------
// Kernel 2 (round-2 proven pattern): per-expert k-th-largest key via FOUR
// 8-bit radix passes over register-resident keys. Per-wave replicated LDS
// histograms (no cross-wave atomic contention); descending 256-bin scan via
// 64-lane shuffle suffix-scan. KPT4=0: streaming fallback for other N.
// ---------------------------------------------------------------------------
template <int KPT4>
__global__ __launch_bounds__(1024) void select_kernel(
    const float* __restrict__ logitsT, unsigned* __restrict__ ukeys,
    int N, int k) {
  __shared__ unsigned hist[16][256];
  __shared__ unsigned s_prefix, s_rem;
  const int e = blockIdx.x;
  const int tid = threadIdx.x;
  const int wid = tid >> 6;

  const float4* src = (const float4*)(logitsT + (size_t)e * N);
  unsigned key[KPT4 > 0 ? KPT4 * 4 : 4];
  if (KPT4 > 0) {
#pragma unroll
    for (int i = 0; i < (KPT4 > 0 ? KPT4 : 1); ++i) {
      float4 v = src[tid + i * 1024];
      key[i * 4 + 0] = fkey(v.x);
      key[i * 4 + 1] = fkey(v.y);
      key[i * 4 + 2] = fkey(v.z);
      key[i * 4 + 3] = fkey(v.w);
    }
  }
  if (tid == 0) { s_prefix = 0u; s_rem = (unsigned)k; }

  for (int r = 0; r < 4; ++r) {
    const int shift = 24 - 8 * r;
    const unsigned maskhi = (r == 0) ? 0u : (0xFFFFFFFFu << (shift + 8));
    // zero all 16 histograms (4096 words, 4/thread)
#pragma unroll
    for (int z = 0; z < 4; ++z) ((unsigned*)hist)[z * 1024 + tid] = 0u;
    __syncthreads();
    const unsigned prefix = s_prefix;
    if (KPT4 > 0) {
#pragma unroll
      for (int i = 0; i < (KPT4 > 0 ? KPT4 * 4 : 1); ++i) {
        unsigned u = key[i];
        if ((u & maskhi) == prefix)
          atomicAdd(&hist[wid][(u >> shift) & 255u], 1u);
      }
    } else {
      for (int i = tid; i < (N >> 2); i += 1024) {
        float4 v = src[i];
        unsigned u0 = fkey(v.x), u1 = fkey(v.y), u2 = fkey(v.z), u3 = fkey(v.w);
        if ((u0 & maskhi) == prefix) atomicAdd(&hist[wid][(u0 >> shift) & 255u], 1u);
        if ((u1 & maskhi) == prefix) atomicAdd(&hist[wid][(u1 >> shift) & 255u], 1u);
        if ((u2 & maskhi) == prefix) atomicAdd(&hist[wid][(u2 >> shift) & 255u], 1u);
        if ((u3 & maskhi) == prefix) atomicAdd(&hist[wid][(u3 >> shift) & 255u], 1u);
      }
    }
    __syncthreads();
    if (tid < 64) {
      unsigned rem = s_rem;
      // lane owns bins tid*4 .. tid*4+3 (higher bin = larger value)
      unsigned h0 = 0, h1 = 0, h2 = 0, h3 = 0;
#pragma unroll
      for (int w = 0; w < 16; ++w) {
        h0 += hist[w][tid * 4 + 0];
        h1 += hist[w][tid * 4 + 1];
        h2 += hist[w][tid * 4 + 2];
        h3 += hist[w][tid * 4 + 3];
      }
      unsigned c3 = h3, c2 = c3 + h2, c1 = c2 + h1, c0 = c1 + h0;
      unsigned cum = c0;  // inclusive suffix over lanes >= tid
#pragma unroll
      for (int off = 1; off < 64; off <<= 1) {
        unsigned v = __shfl_down(cum, off);
        if (tid + off < 64) cum += v;
      }
      unsigned above = cum - c0;  // count in lanes > tid
      if (above < rem && rem <= cum) {  // crossing happens in this lane
        int j; unsigned abv;
        if (above + c3 >= rem)      { j = 3; abv = above; }
        else if (above + c2 >= rem) { j = 2; abv = above + c3; }
        else if (above + c1 >= rem) { j = 1; abv = above + c2; }
        else                        { j = 0; abv = above + c1; }
        s_rem = rem - abv;
        s_prefix = prefix | ((unsigned)(tid * 4 + j) << shift);
      }
    }
    __syncthreads();
  }
  if (tid == 0) ukeys[e] = s_prefix;
}

// ---------------------------------------------------------------------------
// Kernel 3 (round-8 proven): one wave per token; lane = expert.
// ---------------------------------------------------------------------------
__global__ __launch_bounds__(256) void assign_kernel(
    const float* __restrict__ logits, const unsigned* __restrict__ ukeys,
    float* __restrict__ out, int N) {
  const int lane = threadIdx.x & 63;
  const int token = blockIdx.x * 4 + (threadIdx.x >> 6);

  float v = logits[(size_t)token * 64 + lane];
  unsigned u = fkey(v);
  bool cand = (u >= ukeys[lane]);
  float cv = cand ? v : -INFINITY;
  float m = cv;
#pragma unroll
  for (int off = 32; off; off >>= 1) m = fmaxf(m, __shfl_xor(m, off));
  unsigned long long mask = __ballot(cand && (v == m));
  bool sel = (mask != 0ull);
  int minexp = sel ? (__ffsll((long long)mask) - 1) : -1;

  if (lane == 0) {
    out[token] = sel ? m : 0.0f;
    out[N + token] = (float)minexp;
    out[2 * N + token] = sel ? 1.0f : 0.0f;
  }
}

// ---------------------------------------------------------------------------
// Kernel 4 (round-8 proven): counts (LDS histogram, 1 block, float4) + loss.
// ---------------------------------------------------------------------------
__global__ __launch_bounds__(1024) void count_loss_kernel(
    const float* __restrict__ assigned, float* __restrict__ out, int N) {
  __shared__ unsigned hist[16][64];
  const int tid = threadIdx.x;
  const int wid = tid >> 6;
  hist[wid][tid & 63] = 0u;
  __syncthreads();
  const float4* src = (const float4*)assigned;
  for (int i = tid; i < (N >> 2); i += 1024) {
    float4 v = src[i];
    int e0 = (int)v.x, e1 = (int)v.y, e2 = (int)v.z, e3 = (int)v.w;
    if (e0 >= 0) atomicAdd(&hist[wid][e0], 1u);
    if (e1 >= 0) atomicAdd(&hist[wid][e1], 1u);
    if (e2 >= 0) atomicAdd(&hist[wid][e2], 1u);
    if (e3 >= 0) atomicAdd(&hist[wid][e3], 1u);
  }
  __syncthreads();
  if (tid < 64) {
    unsigned c = 0;
#pragma unroll
    for (int w = 0; w < 16; ++w) c += hist[w][tid];
    double cd = (double)c;
    double s = cd;
#pragma unroll
    for (int off = 32; off; off >>= 1) s += __shfl_xor(s, off);
    double mean = s / 64.0;
    double d = cd - mean;
    d = d * d;
#pragma unroll
    for (int off = 32; off; off >>= 1) d += __shfl_xor(d, off);
    if (tid == 0) out[3 * (size_t)N] = (float)((d / 64.0) / (mean + 1e-9));
  }
}

extern "C" void kernel_launch(void* const* d_in, const int* in_sizes, int n_in,
                              void* d_out, int out_size, void* d_ws, size_t ws_size,
                              hipStream_t stream) {
  const float* x = (const float*)d_in[0];
  const float* W = (const float*)d_in[1];
  const float* b = (const float*)d_in[2];

  const int E = in_sizes[2];      // 64
  const int D = in_sizes[1] / E;  // 1024
  const int N = in_sizes[0] / D;  // 32768

  int k = (int)((double)N / (double)(E > 1 ? E : 1) * 1.2);
  if (k < 1) k = 1;
  if (k > N) k = N;               // 614

  const size_t NE = (size_t)N * E;
  float* out = (float*)d_out;

  float* logits = (float*)d_ws;        // N*E fp32 (8 MB)
  float* logitsT = logits + NE;        // N*E fp32 (8 MB)
  unsigned* ukeys = (unsigned*)(logitsT + NE);

  logits_fused_kernel<<<N / 64, 1024, 0, stream>>>(x, W, b, logits, logitsT,
                                                   N, D);
  if (N == 32768)
    select_kernel<8><<<64, 1024, 0, stream>>>(logitsT, ukeys, N, k);
  else
    select_kernel<0><<<64, 1024, 0, stream>>>(logitsT, ukeys, N, k);
  assign_kernel<<<N / 4, 256, 0, stream>>>(logits, ukeys, out, N);
  count_loss_kernel<<<1, 1024, 0, stream>>>(out + N, out, N);
}